// Round 2
// baseline (80.717 us; speedup 1.0000x reference)
//
#include <hip/hip_runtime.h>
#include <hip/hip_bf16.h>
#include <stdint.h>

// Problem dims
#define M_DIM 8000
#define K_DIM 120
#define N_DIM 8000
#define M_PADD 8064   // padded M (and padded N for B^T storage)
#define K_PADD 128    // padded K

typedef __attribute__((ext_vector_type(8))) __bf16 bf16x8;
typedef __attribute__((ext_vector_type(4))) float f32x4;
typedef __attribute__((ext_vector_type(8))) unsigned short u16x8;

__device__ __forceinline__ unsigned short f2bf(float f) {
  unsigned int u = __builtin_bit_cast(unsigned int, f);
  u += 0x7FFFu + ((u >> 16) & 1u);   // round-to-nearest-even
  return (unsigned short)(u >> 16);
}

#define CONV_BLOCKS_PER_SIDE 504   // (8064*16)/256

// Fused converter. Blocks [0,504): A -> Abf. Blocks [504,1008): Bm -> Bbf.
// A [8000][120] f32  ->  Abf [8064][128] bf16, zero-padded, row-swizzled:
//   element (row,k) at byte row*256 + ((2k) ^ ((row&7)<<4)).
// Bm [120][8000] f32 ->  Bbf [8064][128] bf16 = B^T, same swizzle on n.
__global__ __launch_bounds__(256) void conv_ab_kernel(const float* __restrict__ A,
                                                      const float* __restrict__ B,
                                                      unsigned short* __restrict__ Abf,
                                                      unsigned short* __restrict__ Bbf) {
  const int bid = blockIdx.x;
  if (bid < CONV_BLOCKS_PER_SIDE) {
    int t = bid * 256 + threadIdx.x;
    int row = t >> 4;     // 0..8063
    int kg  = t & 15;     // k-group of 8 elems
    u16x8 v = (u16x8)0;
    if (row < M_DIM && kg < 15) {   // kg=14 covers k=112..119; kg=15 is pad
      const float* src = A + (size_t)row * K_DIM + kg * 8;  // 32B-aligned (480%32==0)
      float4 f0 = *(const float4*)(src);
      float4 f1 = *(const float4*)(src + 4);
      v[0] = f2bf(f0.x); v[1] = f2bf(f0.y); v[2] = f2bf(f0.z); v[3] = f2bf(f0.w);
      v[4] = f2bf(f1.x); v[5] = f2bf(f1.y); v[6] = f2bf(f1.z); v[7] = f2bf(f1.w);
    }
    int off = (kg * 16) ^ ((row & 7) << 4);
    *(u16x8*)((char*)Abf + (size_t)row * 256 + off) = v;
  } else {
    int t = (bid - CONV_BLOCKS_PER_SIDE) * 256 + threadIdx.x;
    int kg = t / M_PADD;  // 0..15 (coalesced over n within a block)
    int n  = t % M_PADD;  // 0..8063
    u16x8 v = (u16x8)0;
    if (n < N_DIM && kg < 15) {
      const float* src = B + (size_t)(kg * 8) * N_DIM + n;
#pragma unroll
      for (int j = 0; j < 8; ++j) v[j] = f2bf(src[(size_t)j * N_DIM]);
    }
    int off = (kg * 16) ^ ((n & 7) << 4);
    *(u16x8*)((char*)Bbf + (size_t)n * 256 + off) = v;
  }
}

// 128x128 output tile per block, 8 waves (2x4 of 64x32), single K-tile (K=128).
// 64 KB LDS -> 2 blocks/CU -> 16 waves/CU.
__global__ __launch_bounds__(512) void gemm_bias_kernel(const unsigned short* __restrict__ Abf,
                                                        const unsigned short* __restrict__ Bbf,
                                                        const float* __restrict__ bias,
                                                        float* __restrict__ out) {
  __shared__ __align__(16) char smem[65536];   // As: [0,32K), Bs: [32K,64K)
  const int bn = blockIdx.x;
  const int bm = blockIdx.y;
  const int tid  = threadIdx.x;
  const int lane = tid & 63;
  const int wave = tid >> 6;
  const int wr = wave >> 2;   // 0..1 (row half)
  const int wc = wave & 3;    // 0..3 (col quarter)

  // Stage both 32KB tiles; sources are pre-swizzled so linear LDS works.
  const char* gA = (const char*)Abf + (size_t)bm * 32768;
  const char* gB = (const char*)Bbf + (size_t)bn * 32768;
#pragma unroll
  for (int i = 0; i < 4; ++i) {
    int off = i * 8192 + tid * 16;   // wave-uniform base + lane*16 within each wave
    __builtin_amdgcn_global_load_lds(
        (const __attribute__((address_space(1))) void*)(gA + off),
        (__attribute__((address_space(3))) void*)(smem + off), 16, 0, 0);
    __builtin_amdgcn_global_load_lds(
        (const __attribute__((address_space(1))) void*)(gB + off),
        (__attribute__((address_space(3))) void*)(smem + 32768 + off), 16, 0, 0);
  }
  __syncthreads();   // drains vmcnt before barrier

  f32x4 acc[4][2] = {};
  const int l15 = lane & 15;
  const int kq  = lane >> 4;          // 0..3
#pragma unroll
  for (int ks = 0; ks < 4; ++ks) {
    const int kb = (ks * 32 + kq * 8) * 2;   // byte offset along K (mult of 16)
    bf16x8 a[4], b[2];
#pragma unroll
    for (int m = 0; m < 4; ++m) {
      int row = wr * 64 + m * 16 + l15;
      a[m] = *(const bf16x8*)(smem + (size_t)row * 256 + (kb ^ ((row & 7) << 4)));
    }
#pragma unroll
    for (int n = 0; n < 2; ++n) {
      int row = wc * 32 + n * 16 + l15;
      b[n] = *(const bf16x8*)(smem + 32768 + (size_t)row * 256 + (kb ^ ((row & 7) << 4)));
    }
#pragma unroll
    for (int m = 0; m < 4; ++m)
#pragma unroll
      for (int n = 0; n < 2; ++n)
        acc[m][n] = __builtin_amdgcn_mfma_f32_16x16x32_bf16(a[m], b[n], acc[m][n], 0, 0, 0);
  }

  // Epilogue: C/D layout col = lane&15, row = (lane>>4)*4 + reg  [m89-verified]
  const int row0 = bm * 128 + wr * 64 + kq * 4;
  const int col0 = bn * 128 + wc * 32;
#pragma unroll
  for (int n = 0; n < 2; ++n) {
    const int gcol = col0 + n * 16 + l15;
    if (gcol >= N_DIM) continue;            // wave-uniform (8000 % 16 == 0)
    const float bv = bias[gcol];
#pragma unroll
    for (int m = 0; m < 4; ++m) {
      const int grow = row0 + m * 16;
#pragma unroll
      for (int r = 0; r < 4; ++r)
        out[(size_t)(grow + r) * N_DIM + gcol] = acc[m][n][r] + bv;
    }
  }
}

// Safety net if ws_size is too small for the bf16 staging buffers.
__global__ __launch_bounds__(256) void fallback_kernel(const float* __restrict__ A,
                                                       const float* __restrict__ B,
                                                       const float* __restrict__ bias,
                                                       float* __restrict__ out) {
  size_t idx = (size_t)blockIdx.x * 256 + threadIdx.x;
  if (idx >= (size_t)M_PADD * N_DIM) return;
  int col = (int)(idx % N_DIM);
  int row = (int)(idx / N_DIM);
  float s = 0.f;
  if (row < M_DIM) {
    for (int k = 0; k < K_DIM; ++k)
      s += A[(size_t)row * K_DIM + k] * B[(size_t)k * N_DIM + col];
  }
  out[idx] = s + bias[col];
}

extern "C" void kernel_launch(void* const* d_in, const int* in_sizes, int n_in,
                              void* d_out, int out_size, void* d_ws, size_t ws_size,
                              hipStream_t stream) {
  const float* A    = (const float*)d_in[0];
  const float* Bm   = (const float*)d_in[1];
  const float* bias = (const float*)d_in[2];
  float* out = (float*)d_out;

  const size_t abf_elems = (size_t)M_PADD * K_PADD;            // 1,032,192
  const size_t need = abf_elems * 2 * sizeof(unsigned short);  // ~4.13 MB
  if (ws_size < need) {
    size_t total = (size_t)M_PADD * N_DIM;
    fallback_kernel<<<dim3((unsigned)((total + 255) / 256)), dim3(256), 0, stream>>>(A, Bm, bias, out);
    return;
  }

  unsigned short* Abf = (unsigned short*)d_ws;
  unsigned short* Bbf = Abf + abf_elems;   // 16B-aligned (offset 2,064,384 elems)

  conv_ab_kernel<<<dim3(2 * CONV_BLOCKS_PER_SIDE), dim3(256), 0, stream>>>(A, Bm, Abf, Bbf);
  gemm_bias_kernel<<<dim3(63, 63), dim3(512), 0, stream>>>(Abf, Bbf, bias, out);
}

// Round 3
// 58.660 us; speedup vs baseline: 1.3760x; 1.3760x over previous
//
#include <hip/hip_runtime.h>
#include <hip/hip_bf16.h>
#include <stdint.h>

// Problem dims
#define M_DIM 8000
#define K_DIM 120
#define N_DIM 8000
#define M_PADD 8064   // padded M (and padded N for B^T storage)
#define K_PADD 128    // padded K

typedef __attribute__((ext_vector_type(8))) __bf16 bf16x8;
typedef __attribute__((ext_vector_type(4))) float f32x4;
typedef __attribute__((ext_vector_type(8))) unsigned short u16x8;

__device__ __forceinline__ unsigned short f2bf(float f) {
  unsigned int u = __builtin_bit_cast(unsigned int, f);
  u += 0x7FFFu + ((u >> 16) & 1u);   // round-to-nearest-even
  return (unsigned short)(u >> 16);
}

#define CONV_BLOCKS_PER_SIDE 504   // (8064*16)/256

// Fused converter. Blocks [0,504): A -> Abf. Blocks [504,1008): Bm -> Bbf.
// A [8000][120] f32  ->  Abf [8064][128] bf16, zero-padded, row-swizzled:
//   element (row,k) at byte row*256 + ((2k) ^ ((row&7)<<4)).
// Bm [120][8000] f32 ->  Bbf [8064][128] bf16 = B^T, same swizzle on n.
__global__ __launch_bounds__(256) void conv_ab_kernel(const float* __restrict__ A,
                                                      const float* __restrict__ B,
                                                      unsigned short* __restrict__ Abf,
                                                      unsigned short* __restrict__ Bbf) {
  const int bid = blockIdx.x;
  if (bid < CONV_BLOCKS_PER_SIDE) {
    int t = bid * 256 + threadIdx.x;
    int row = t >> 4;     // 0..8063
    int kg  = t & 15;     // k-group of 8 elems
    u16x8 v = (u16x8)0;
    if (row < M_DIM && kg < 15) {   // kg=14 covers k=112..119; kg=15 is pad
      const float* src = A + (size_t)row * K_DIM + kg * 8;  // 32B-aligned (480%32==0)
      float4 f0 = *(const float4*)(src);
      float4 f1 = *(const float4*)(src + 4);
      v[0] = f2bf(f0.x); v[1] = f2bf(f0.y); v[2] = f2bf(f0.z); v[3] = f2bf(f0.w);
      v[4] = f2bf(f1.x); v[5] = f2bf(f1.y); v[6] = f2bf(f1.z); v[7] = f2bf(f1.w);
    }
    int off = (kg * 16) ^ ((row & 7) << 4);
    *(u16x8*)((char*)Abf + (size_t)row * 256 + off) = v;
  } else {
    int t = (bid - CONV_BLOCKS_PER_SIDE) * 256 + threadIdx.x;
    int kg = t / M_PADD;  // 0..15 (coalesced over n within a block)
    int n  = t % M_PADD;  // 0..8063
    u16x8 v = (u16x8)0;
    if (n < N_DIM && kg < 15) {
      const float* src = B + (size_t)(kg * 8) * N_DIM + n;
#pragma unroll
      for (int j = 0; j < 8; ++j) v[j] = f2bf(src[(size_t)j * N_DIM]);
    }
    int off = (kg * 16) ^ ((n & 7) << 4);
    *(u16x8*)((char*)Bbf + (size_t)n * 256 + off) = v;
  }
}

// 128x128 output tile per block, 8 waves (2x4 of 64x32), single K-tile (K=128).
// Epilogue: acc -> LDS transpose -> contiguous 1KB-per-instruction dwordx4 stores.
__global__ __launch_bounds__(512) void gemm_bias_kernel(const unsigned short* __restrict__ Abf,
                                                        const unsigned short* __restrict__ Bbf,
                                                        const float* __restrict__ bias,
                                                        float* __restrict__ out) {
  __shared__ __align__(16) char smem[65536];   // As: [0,32K), Bs: [32K,64K); reused by epilogue
  const int bn = blockIdx.x;
  const int bm = blockIdx.y;
  const int tid  = threadIdx.x;
  const int lane = tid & 63;
  const int wave = tid >> 6;
  const int wr = wave >> 2;   // 0..1 (row half)
  const int wc = wave & 3;    // 0..3 (col quarter)

  // Stage both 32KB tiles; sources are pre-swizzled so linear LDS works.
  const char* gA = (const char*)Abf + (size_t)bm * 32768;
  const char* gB = (const char*)Bbf + (size_t)bn * 32768;
#pragma unroll
  for (int i = 0; i < 4; ++i) {
    int off = i * 8192 + tid * 16;   // wave-uniform base + lane*16 within each wave
    __builtin_amdgcn_global_load_lds(
        (const __attribute__((address_space(1))) void*)(gA + off),
        (__attribute__((address_space(3))) void*)(smem + off), 16, 0, 0);
    __builtin_amdgcn_global_load_lds(
        (const __attribute__((address_space(1))) void*)(gB + off),
        (__attribute__((address_space(3))) void*)(smem + 32768 + off), 16, 0, 0);
  }
  __syncthreads();   // drains vmcnt before barrier

  f32x4 acc[4][2] = {};
  const int l15 = lane & 15;
  const int kq  = lane >> 4;          // 0..3
#pragma unroll
  for (int ks = 0; ks < 4; ++ks) {
    const int kb = (ks * 32 + kq * 8) * 2;   // byte offset along K (mult of 16)
    bf16x8 a[4], b[2];
#pragma unroll
    for (int m = 0; m < 4; ++m) {
      int row = wr * 64 + m * 16 + l15;
      a[m] = *(const bf16x8*)(smem + (size_t)row * 256 + (kb ^ ((row & 7) << 4)));
    }
#pragma unroll
    for (int n = 0; n < 2; ++n) {
      int row = wc * 32 + n * 16 + l15;
      b[n] = *(const bf16x8*)(smem + 32768 + (size_t)row * 256 + (kb ^ ((row & 7) << 4)));
    }
#pragma unroll
    for (int m = 0; m < 4; ++m)
#pragma unroll
      for (int n = 0; n < 2; ++n)
        acc[m][n] = __builtin_amdgcn_mfma_f32_16x16x32_bf16(a[m], b[n], acc[m][n], 0, 0, 0);
  }

  // ---- Epilogue ----
  // C/D layout: col = lane&15, row_in_16 = (lane>>4)*4 + reg   [m89-verified]
  // Bias per lane's two columns (guard OOB cols of the last tile).
  float bv[2];
#pragma unroll
  for (int n = 0; n < 2; ++n) {
    int gcol = bn * 128 + wc * 32 + n * 16 + l15;
    bv[n] = (gcol < N_DIM) ? bias[gcol] : 0.f;
  }

  // Transpose buffer: [64][132] f32 (pad +4 dwords -> 2-way-free banks both sides).
  float* tbuf = (float*)smem;
#pragma unroll
  for (int h = 0; h < 2; ++h) {
    __syncthreads();                 // previous smem users done
    if (wr == h) {                   // wave-uniform branch
#pragma unroll
      for (int m = 0; m < 4; ++m)
#pragma unroll
        for (int n = 0; n < 2; ++n)
#pragma unroll
          for (int r = 0; r < 4; ++r) {
            int rl = m * 16 + kq * 4 + r;        // 0..63 (row within half-tile)
            int c  = wc * 32 + n * 16 + l15;     // 0..127
            tbuf[rl * 132 + c] = acc[m][n][r] + bv[n];
          }
    }
    __syncthreads();
    // All 8 waves stream 64 rows x 512B: instr j covers 2 full rows (1KB contiguous).
#pragma unroll
    for (int j = 0; j < 4; ++j) {
      int rl = (wave * 4 + j) * 2 + (lane >> 5);   // 0..63
      int c  = lane & 31;                           // 16-B chunk within row
      f32x4 v = *(const f32x4*)(tbuf + rl * 132 + c * 4);
      int gcol = bn * 128 + c * 4;
      if (gcol < N_DIM) {                           // chunk fully valid (8000 % 4 == 0)
        size_t off = (size_t)(bm * 128 + h * 64 + rl) * N_DIM + gcol;
        __builtin_nontemporal_store(v, (f32x4*)(out + off));
      }
    }
  }
}

// Safety net if ws_size is too small for the bf16 staging buffers.
__global__ __launch_bounds__(256) void fallback_kernel(const float* __restrict__ A,
                                                       const float* __restrict__ B,
                                                       const float* __restrict__ bias,
                                                       float* __restrict__ out) {
  size_t idx = (size_t)blockIdx.x * 256 + threadIdx.x;
  if (idx >= (size_t)M_PADD * N_DIM) return;
  int col = (int)(idx % N_DIM);
  int row = (int)(idx / N_DIM);
  float s = 0.f;
  if (row < M_DIM) {
    for (int k = 0; k < K_DIM; ++k)
      s += A[(size_t)row * K_DIM + k] * B[(size_t)k * N_DIM + col];
  }
  out[idx] = s + bias[col];
}

extern "C" void kernel_launch(void* const* d_in, const int* in_sizes, int n_in,
                              void* d_out, int out_size, void* d_ws, size_t ws_size,
                              hipStream_t stream) {
  const float* A    = (const float*)d_in[0];
  const float* Bm   = (const float*)d_in[1];
  const float* bias = (const float*)d_in[2];
  float* out = (float*)d_out;

  const size_t abf_elems = (size_t)M_PADD * K_PADD;            // 1,032,192
  const size_t need = abf_elems * 2 * sizeof(unsigned short);  // ~4.13 MB
  if (ws_size < need) {
    size_t total = (size_t)M_PADD * N_DIM;
    fallback_kernel<<<dim3((unsigned)((total + 255) / 256)), dim3(256), 0, stream>>>(A, Bm, bias, out);
    return;
  }

  unsigned short* Abf = (unsigned short*)d_ws;
  unsigned short* Bbf = Abf + abf_elems;   // 16B-aligned offset

  conv_ab_kernel<<<dim3(2 * CONV_BLOCKS_PER_SIDE), dim3(256), 0, stream>>>(A, Bm, Abf, Bbf);
  gemm_bias_kernel<<<dim3(63, 63), dim3(512), 0, stream>>>(Abf, Bbf, bias, out);
}

// Round 4
// 57.382 us; speedup vs baseline: 1.4067x; 1.0223x over previous
//
#include <hip/hip_runtime.h>
#include <hip/hip_bf16.h>
#include <stdint.h>

// Problem dims
#define M_DIM 8000
#define K_DIM 120
#define N_DIM 8000
#define M_PADD 8064   // padded M for Abf
#define N_PADB 8192   // padded N for Bbf (so BN=256 tiles stage cleanly)
#define K_PADD 128

typedef __attribute__((ext_vector_type(8))) __bf16 bf16x8;
typedef __attribute__((ext_vector_type(4))) float f32x4;
typedef __attribute__((ext_vector_type(8))) unsigned short u16x8;

__device__ __forceinline__ unsigned short f2bf(float f) {
  unsigned int u = __builtin_bit_cast(unsigned int, f);
  u += 0x7FFFu + ((u >> 16) & 1u);   // round-to-nearest-even
  return (unsigned short)(u >> 16);
}

#define CONV_A_BLOCKS 504   // 8064*16/256
#define CONV_B_BLOCKS 512   // 8192*16/256

// Fused converter. Blocks [0,504): A -> Abf. Blocks [504,1016): Bm -> Bbf.
// Abf [8064][128] bf16, zero-padded, row-swizzled:
//   element (row,k) at byte row*256 + ((2k) ^ ((row&7)<<4)).
// Bbf [8192][128] bf16 = B^T, zero-padded (rows >= 8000 all-zero), same swizzle.
__global__ __launch_bounds__(256) void conv_ab_kernel(const float* __restrict__ A,
                                                      const float* __restrict__ B,
                                                      unsigned short* __restrict__ Abf,
                                                      unsigned short* __restrict__ Bbf) {
  const int bid = blockIdx.x;
  if (bid < CONV_A_BLOCKS) {
    int t = bid * 256 + threadIdx.x;
    int row = t >> 4;     // 0..8063
    int kg  = t & 15;     // k-group of 8 elems
    u16x8 v = (u16x8)0;
    if (row < M_DIM && kg < 15) {   // kg=14 covers k=112..119; kg=15 is pad
      const float* src = A + (size_t)row * K_DIM + kg * 8;  // 32B-aligned (480%32==0)
      float4 f0 = *(const float4*)(src);
      float4 f1 = *(const float4*)(src + 4);
      v[0] = f2bf(f0.x); v[1] = f2bf(f0.y); v[2] = f2bf(f0.z); v[3] = f2bf(f0.w);
      v[4] = f2bf(f1.x); v[5] = f2bf(f1.y); v[6] = f2bf(f1.z); v[7] = f2bf(f1.w);
    }
    int off = (kg * 16) ^ ((row & 7) << 4);
    *(u16x8*)((char*)Abf + (size_t)row * 256 + off) = v;
  } else {
    int t = (bid - CONV_A_BLOCKS) * 256 + threadIdx.x;
    int kg = t / N_PADB;  // 0..15 (coalesced over n within a block)
    int n  = t % N_PADB;  // 0..8191
    u16x8 v = (u16x8)0;
    if (n < N_DIM && kg < 15) {
      const float* src = B + (size_t)(kg * 8) * N_DIM + n;
#pragma unroll
      for (int j = 0; j < 8; ++j) v[j] = f2bf(src[(size_t)j * N_DIM]);
    }
    int off = (kg * 16) ^ ((n & 7) << 4);
    *(u16x8*)((char*)Bbf + (size_t)n * 256 + off) = v;
  }
}

// 64x256 output tile per block, 8 waves (1x8), single K-tile (K=128).
// LDS: As 16KB + Bs 64KB = 80KB -> 2 blocks/CU. Epilogue tbuf overlays As/Bs.
// Each store instruction = one fully contiguous 1KB output row-chunk.
__global__ __launch_bounds__(512, 4) void gemm_bias_kernel(const unsigned short* __restrict__ Abf,
                                                           const unsigned short* __restrict__ Bbf,
                                                           const float* __restrict__ bias,
                                                           float* __restrict__ out) {
  __shared__ __align__(16) char smem[81920];   // As: [0,16K), Bs: [16K,80K)
  const int bn = blockIdx.x;   // 0..31  (256-col tiles)
  const int bm = blockIdx.y;   // 0..125 (64-row tiles)
  const int tid  = threadIdx.x;
  const int lane = tid & 63;
  const int wave = tid >> 6;   // 0..7 == column slot (wc)

  // Stage tiles; sources are pre-swizzled so linear LDS staging works.
  const char* gA = (const char*)Abf + (size_t)bm * 16384;
  const char* gB = (const char*)Bbf + (size_t)bn * 65536;
#pragma unroll
  for (int i = 0; i < 2; ++i) {
    int off = i * 8192 + tid * 16;
    __builtin_amdgcn_global_load_lds(
        (const __attribute__((address_space(1))) void*)(gA + off),
        (__attribute__((address_space(3))) void*)(smem + off), 16, 0, 0);
  }
#pragma unroll
  for (int i = 0; i < 8; ++i) {
    int off = i * 8192 + tid * 16;
    __builtin_amdgcn_global_load_lds(
        (const __attribute__((address_space(1))) void*)(gB + off),
        (__attribute__((address_space(3))) void*)(smem + 16384 + off), 16, 0, 0);
  }
  __syncthreads();   // drains vmcnt before barrier

  f32x4 acc[4][2] = {};
  const int l15 = lane & 15;
  const int kq  = lane >> 4;          // 0..3
#pragma unroll
  for (int ks = 0; ks < 4; ++ks) {
    const int kb = (ks * 32 + kq * 8) * 2;   // byte offset along K (mult of 16)
    bf16x8 a[4], b[2];
#pragma unroll
    for (int m = 0; m < 4; ++m) {
      int row = m * 16 + l15;                // 0..63 (all waves share A rows)
      a[m] = *(const bf16x8*)(smem + (size_t)row * 256 + (kb ^ ((row & 7) << 4)));
    }
#pragma unroll
    for (int n = 0; n < 2; ++n) {
      int row = wave * 32 + n * 16 + l15;    // 0..255
      b[n] = *(const bf16x8*)(smem + 16384 + (size_t)row * 256 + (kb ^ ((row & 7) << 4)));
    }
#pragma unroll
    for (int m = 0; m < 4; ++m)
#pragma unroll
      for (int n = 0; n < 2; ++n)
        acc[m][n] = __builtin_amdgcn_mfma_f32_16x16x32_bf16(a[m], b[n], acc[m][n], 0, 0, 0);
  }

  // ---- Epilogue ----
  // C/D layout: col = lane&15, row_in_16 = (lane>>4)*4 + reg   [m89-verified]
  float bv[2];
#pragma unroll
  for (int n = 0; n < 2; ++n) {
    int gcol = bn * 256 + wave * 32 + n * 16 + l15;
    bv[n] = (gcol < N_DIM) ? bias[gcol] : 0.f;
  }

  // Transpose buffer overlays As/Bs: [64][260] f32 (66.5KB <= 80KB).
  float* tbuf = (float*)smem;
  __syncthreads();                 // all compute reads of As/Bs done
#pragma unroll
  for (int m = 0; m < 4; ++m)
#pragma unroll
    for (int n = 0; n < 2; ++n)
#pragma unroll
      for (int r = 0; r < 4; ++r) {
        int rl = m * 16 + kq * 4 + r;          // 0..63
        int c  = wave * 32 + n * 16 + l15;     // 0..255
        tbuf[rl * 260 + c] = acc[m][n][r] + bv[n];
      }
  __syncthreads();

  // Stream out: each pass, each wave stores one full row-chunk (1KB contiguous).
  const int gcol0 = bn * 256 + lane * 4;
  const bool colok = (gcol0 < N_DIM);          // chunk fully valid (8000%4==0)
#pragma unroll
  for (int j = 0; j < 8; ++j) {
    int row = j * 8 + wave;                    // 0..63
    f32x4 v = *(const f32x4*)(tbuf + row * 260 + lane * 4);
    if (colok) {
      size_t off = (size_t)(bm * 64 + row) * N_DIM + gcol0;
      __builtin_nontemporal_store(v, (f32x4*)(out + off));
    }
  }
}

// Safety net if ws_size is too small for the bf16 staging buffers.
__global__ __launch_bounds__(256) void fallback_kernel(const float* __restrict__ A,
                                                       const float* __restrict__ B,
                                                       const float* __restrict__ bias,
                                                       float* __restrict__ out) {
  size_t idx = (size_t)blockIdx.x * 256 + threadIdx.x;
  if (idx >= (size_t)M_PADD * N_DIM) return;
  int col = (int)(idx % N_DIM);
  int row = (int)(idx / N_DIM);
  float s = 0.f;
  if (row < M_DIM) {
    for (int k = 0; k < K_DIM; ++k)
      s += A[(size_t)row * K_DIM + k] * B[(size_t)k * N_DIM + col];
  }
  out[idx] = s + bias[col];
}

extern "C" void kernel_launch(void* const* d_in, const int* in_sizes, int n_in,
                              void* d_out, int out_size, void* d_ws, size_t ws_size,
                              hipStream_t stream) {
  const float* A    = (const float*)d_in[0];
  const float* Bm   = (const float*)d_in[1];
  const float* bias = (const float*)d_in[2];
  float* out = (float*)d_out;

  const size_t abf_elems = (size_t)M_PADD * K_PADD;   // 1,032,192
  const size_t bbf_elems = (size_t)N_PADB * K_PADD;   // 1,048,576
  const size_t need = (abf_elems + bbf_elems) * sizeof(unsigned short);  // ~4.16 MB
  if (ws_size < need) {
    size_t total = (size_t)M_PADD * N_DIM;
    fallback_kernel<<<dim3((unsigned)((total + 255) / 256)), dim3(256), 0, stream>>>(A, Bm, bias, out);
    return;
  }

  unsigned short* Abf = (unsigned short*)d_ws;
  unsigned short* Bbf = Abf + abf_elems;   // 16B-aligned offset

  conv_ab_kernel<<<dim3(CONV_A_BLOCKS + CONV_B_BLOCKS), dim3(256), 0, stream>>>(A, Bm, Abf, Bbf);
  gemm_bias_kernel<<<dim3(32, 126), dim3(512), 0, stream>>>(Abf, Bbf, bias, out);
}